// Round 13
// baseline (924.358 us; speedup 1.0000x reference)
//
#include <hip/hip_runtime.h>
#include <hip/hip_bf16.h>

// Problem constants
#define B_Q    2048
#define C_CLS  1000
#define D_DIM  512
#define N_BANK 100000
#define KSEL   10
#define NPAD   100096            // N_BANK padded to multiple of 128
#define NBLKS  782               // NPAD / 128
#define NBLOCKS (16 * NBLKS)     // 12512 workgroups (12512 % 8 == 0)
#define PROW   (NBLKS * 6)       // 4692 partial floats per query row

typedef __attribute__((ext_vector_type(4))) float  float4v;
typedef __attribute__((ext_vector_type(8))) int    int8v;
typedef unsigned short u16;
typedef unsigned int   u32;
typedef unsigned char  u8;

// ---------- helpers ----------

// f32 -> e4m3fn (OCP), RNE, flush |x|<2^-6 to 0 (inputs are N(0,1): negligible)
__device__ __forceinline__ u32 f2e4m3(float f) {
  union { float f; u32 u; } v; v.f = f;
  u32 u = v.u;
  u32 s = (u >> 24) & 0x80u;
  u32 a = u & 0x7FFFFFFFu;
  a += 0x7FFFFu + ((a >> 20) & 1u);        // RNE into 3-bit mantissa
  int e8 = (int)((a >> 23) & 0xFF) - 120;  // -127 + 7
  u32 r;
  if (e8 <= 0)       r = 0;
  else if (e8 >= 16) r = 0x7E;             // clamp to 448 (unreachable here)
  else               r = ((u32)e8 << 3) | ((a >> 20) & 7u);
  return s | r;
}

__device__ __forceinline__ u32 pack4_e4m3(float4 f) {
  return f2e4m3(f.x) | (f2e4m3(f.y) << 8) | (f2e4m3(f.z) << 16) | (f2e4m3(f.w) << 24);
}

__device__ __forceinline__ void chain10(float (&t)[10], float v) {
#pragma unroll
  for (int j = 0; j < 10; ++j) {
    float o = t[j];
    t[j] = fmaxf(o, v);
    v    = fminf(o, v);
  }
}

__device__ __forceinline__ void chain3(float (&t)[3], float v) {
#pragma unroll
  for (int j = 0; j < 3; ++j) {
    float o = t[j];
    t[j] = fmaxf(o, v);
    v    = fminf(o, v);
  }
}

__device__ __forceinline__ void load16(const u8* g, u8* l) {
  __builtin_amdgcn_global_load_lds(
      (const __attribute__((address_space(1))) unsigned int*)g,
      (__attribute__((address_space(3))) unsigned int*)l, 16, 0, 0);
}

// Permuted fp8 chunk writer for the BK=128 layout (proven R12, absmax 8.0).
// Row layout: 512 B = 4 K-tiles x 128 B; K-tile = 8 slots of 16 B.
// Physical slot p holds logical slot L = p ^ (row&7). GEMM reads lo = L=g
// (p = g^swz8), hi = L=g+4 (p^4): 16 rows x 8 slots cover all 32 banks 2x
// -> conflict-free b128. Same permutation on A and B (any K-remap cancels).
__device__ __forceinline__ void cvt_chunk(const float* __restrict__ src,
                                          u8* __restrict__ dst, long idx, int nrows) {
  const int row = (int)(idx >> 5);
  const int c5  = (int)(idx & 31);
  const int kt  = c5 >> 3, p = c5 & 7;
  uint4 w;
  if (row < nrows) {
    const int L = p ^ (row & 7);
    const float* q = src + (long)row * D_DIM + kt * 128 + L * 16;
    w = make_uint4(pack4_e4m3(*(const float4*)(q)),
                   pack4_e4m3(*(const float4*)(q + 4)),
                   pack4_e4m3(*(const float4*)(q + 8)),
                   pack4_e4m3(*(const float4*)(q + 12)));
  } else {
    w = make_uint4(0, 0, 0, 0);
  }
  *(uint4*)(dst + idx * 16) = w;
}

// ---------- kernel 1: fused lse (0..2047) + feat cvt (2048..2303) + bank cvt ----------

__global__ __launch_bounds__(256) void pre_kernel(const float* __restrict__ logits,
                                                  float* __restrict__ confs,
                                                  const float* __restrict__ features,
                                                  u8* __restrict__ featb8,
                                                  const float* __restrict__ bank,
                                                  u8* __restrict__ bankb8) {
  const int tid = threadIdx.x;
  if (blockIdx.x < B_Q) {
    const int b = blockIdx.x;
    const int wid = tid >> 6, lane = tid & 63;
    const float* row = logits + (long)b * C_CLS;
    float x[4];
    float m = -INFINITY;
#pragma unroll
    for (int k = 0; k < 4; ++k) {
      int c = tid + k * 256;
      x[k] = (c < C_CLS) ? row[c] : -INFINITY;
      m = fmaxf(m, x[k]);
    }
#pragma unroll
    for (int off = 32; off; off >>= 1) m = fmaxf(m, __shfl_xor(m, off));
    __shared__ float redm[4], reds[4];
    if (lane == 0) redm[wid] = m;
    __syncthreads();
    m = fmaxf(fmaxf(redm[0], redm[1]), fmaxf(redm[2], redm[3]));
    float s = 0.f;
#pragma unroll
    for (int k = 0; k < 4; ++k) {
      int c = tid + k * 256;
      if (c < C_CLS) s += expf(x[k] - m);
    }
#pragma unroll
    for (int off = 32; off; off >>= 1) s += __shfl_xor(s, off);
    if (lane == 0) reds[wid] = s;
    __syncthreads();
    if (tid == 0) confs[b] = m + logf(reds[0] + reds[1] + reds[2] + reds[3]);
  } else if (blockIdx.x < B_Q + 256) {
    // feat cvt: 256 blocks = 65536 chunks (2048 rows x 32)
    long idx = (long)(blockIdx.x - B_Q) * 256 + tid;
    cvt_chunk(features, featb8, idx, B_Q);
  } else {
    // bank cvt: 12512 blocks = NPAD*32 chunks (pad rows zero-filled)
    long idx = (long)(blockIdx.x - B_Q - 256) * 256 + tid;
    cvt_chunk(bank, bankb8, idx, N_BANK);
  }
}

// ---------- epilogue helper: per-query top-3 over the wave's 64 banks ----------
// D (16x16 C/D layout, shape-determined): row = bank frag (g*4+reg), col = query
// (r16). chain3 over 16 lane-local values, merge across g-lanes via shfl 16/32.

template <bool MASKED>
__device__ __forceinline__ void epi(const float4v (&acc)[4][4], int bankbase,
                                    int qbase, int nblk, int wm, int g, int r16,
                                    float* __restrict__ partials) {
#pragma unroll
  for (int n = 0; n < 4; ++n) {
    float t3[3] = {-INFINITY, -INFINITY, -INFINITY};
#pragma unroll
    for (int mq = 0; mq < 4; ++mq)
#pragma unroll
      for (int reg = 0; reg < 4; ++reg) {
        float v = acc[mq][n][reg];
        if (MASKED) v = (bankbase + mq * 16 + reg < N_BANK) ? v : -INFINITY;
        chain3(t3, v);
      }
#pragma unroll
    for (int xm = 16; xm <= 32; xm <<= 1) {
      float o0 = __shfl_xor(t3[0], xm);
      float o1 = __shfl_xor(t3[1], xm);
      float o2 = __shfl_xor(t3[2], xm);
      chain3(t3, o0); chain3(t3, o1); chain3(t3, o2);
    }
    if (g == n) {
      const int q = qbase + n * 16 + r16;
      float* dst = partials + (long)q * PROW + nblk * 6 + wm * 3;
      dst[0] = t3[0]; dst[1] = t3[1]; dst[2] = t3[2];
    }
  }
}

// ---------- kernel 3: 128x128 MX-scaled fp8 GEMM, single-buffered ----------
//
// R12's MX arithmetic (mfma_scale_f32_16x16x128_f8f6f4, unit scales 0x7F,
// proven absmax 8.0) with LDS halved to 32 KB SINGLE-buffered -> 4 blocks/CU
// (R12's 64 KB dbuf gave 2 blocks/CU and the occupancy loss ate the entire
// 2.26x MFMA-rate win). Only 4 K-tiles: per tile {STAGE 8 load16 -> vmcnt(0)
// + s_barrier -> frag ds_reads + 16 MFMA -> s_barrier}; the full drain per
// tile is covered by 4 co-resident blocks (R5-proven regime).
// Global fp8 buffers pre-permuted (cvt_chunk): staging linear, swizzle baked.
// Swapped operands: D = sim[bank][query]. T1 XCD swizzle bijective.

struct __align__(16) SmemT {
  u8 A[128][128];   // 16 KB
  u8 B[128][128];   // 16 KB
};

__global__ __launch_bounds__(256, 4) void gemm_topk_kernel(const u8* __restrict__ featb8,
                                                           const u8* __restrict__ bankb8,
                                                           float* __restrict__ partials) {
  __shared__ SmemT sm;
  // T1: XCD-chunked bijective remap (XCD = blockIdx % 8 round-robin)
  const int orig = blockIdx.x;
  const int swid = (orig & 7) * (NBLOCKS / 8) + (orig >> 3);
  const int mblk = swid & 15;          // x-major: linear = mblk + 16*nblk
  const int nblk = swid >> 4;          // 0..781

  const int tid  = threadIdx.x;
  const int lane = tid & 63;
  const int wid  = tid >> 6;
  const int wm   = wid >> 1, wn = wid & 1;   // wave: banks wm*64.., queries wn*64..
  const int g    = lane >> 4, r16 = lane & 15;
  const int swz8 = r16 & 7;            // read-side slot-XOR term

  const u8* Ag = featb8 + (long)mblk * 128 * D_DIM;   // A = query tile (fp8, permuted)
  const u8* Bg = bankb8 + (long)nblk * 128 * D_DIM;   // B = bank tile  (fp8, permuted)

  float4v acc[4][4];                   // acc[mq][n]: mq = bank frag, n = query frag
  const float4v zero = {0.f, 0.f, 0.f, 0.f};
#pragma unroll
  for (int m = 0; m < 4; ++m)
#pragma unroll
    for (int n = 0; n < 4; ++n) acc[m][n] = zero;

  // staging: per K-tile each matrix is 1024 chunks of 16 B (row = c>>3, p = c&7);
  // buffers pre-permuted -> source linear: row*512 + kt*128 + p*16. 4 chunks/thread.
  long soff[4];
#pragma unroll
  for (int j = 0; j < 4; ++j) {
    const int c = tid + j * 256;
    soff[j] = (long)(c >> 3) * D_DIM + (c & 7) * 16;
  }

#define STAGE(ktv) do {                                                        \
    const int _k = (ktv) * 128;                                                \
    _Pragma("unroll")                                                          \
    for (int j = 0; j < 4; ++j)                                                \
      load16(Ag + soff[j] + _k, &sm.A[0][0] + (tid + j * 256) * 16);           \
    _Pragma("unroll")                                                          \
    for (int j = 0; j < 4; ++j)                                                \
      load16(Bg + soff[j] + _k, &sm.B[0][0] + (tid + j * 256) * 16);           \
  } while (0)

  // fragment: lo = logical slot g (p = g^swz8), hi = slot g+4 (p ^ 4)
#define FRAG(dstv, Mat, rowv) do {                                             \
    const u8* base_ = &sm.Mat[rowv][0];                                        \
    union { int8v v; uint4 q[2]; } u_;                                         \
    u_.q[0] = *(const uint4*)(base_ + ((g ^ swz8) * 16));                      \
    u_.q[1] = *(const uint4*)(base_ + (((g ^ swz8) ^ 4) * 16));                \
    dstv = u_.v;                                                               \
  } while (0)

#pragma unroll
  for (int kt = 0; kt < 4; ++kt) {
    STAGE(kt);
    asm volatile("s_waitcnt vmcnt(0)" ::: "memory");
    __builtin_amdgcn_s_barrier();
    __builtin_amdgcn_sched_barrier(0);
    {
      int8v af[4];
#pragma unroll
      for (int n = 0; n < 4; ++n) FRAG(af[n], A, wn * 64 + n * 16 + r16);
#pragma unroll
      for (int mq = 0; mq < 4; ++mq) {
        int8v bb;
        FRAG(bb, B, wm * 64 + mq * 16 + r16);
#pragma unroll
        for (int n = 0; n < 4; ++n)
          acc[mq][n] = __builtin_amdgcn_mfma_scale_f32_16x16x128_f8f6f4(
              bb, af[n], acc[mq][n], 0, 0, 0, 0x7F7F7F7F, 0, 0x7F7F7F7F);
      }
    }
    __builtin_amdgcn_sched_barrier(0);
    if (kt < 3) {
      __builtin_amdgcn_s_barrier();      // all waves done reading before overwrite
      __builtin_amdgcn_sched_barrier(0);
    }
  }

#undef STAGE
#undef FRAG

  // ---- in-register epilogue (uniform branch: pad masking only on last nblk) ----
  const int bankbase = nblk * 128 + wm * 64 + g * 4;
  const int qbase    = mblk * 128 + wn * 64;
  if (nblk == NBLKS - 1)
    epi<true >(acc, bankbase, qbase, nblk, wm, g, r16, partials);
  else
    epi<false>(acc, bankbase, qbase, nblk, wm, g, r16, partials);
}

// ---------- kernel 4: merge 782*6 partial values per row, scale, write out ----------

__global__ __launch_bounds__(256) void merge_kernel(const float* __restrict__ partials,
                                                    const float* __restrict__ confs,
                                                    float* __restrict__ out) {
  __shared__ float L[256][10];
  const int b = blockIdx.x, tid = threadIdx.x;
  const float4* row = (const float4*)(partials + (long)b * PROW);
  float t[10];
#pragma unroll
  for (int j = 0; j < 10; ++j) t[j] = -INFINITY;
  for (int idx = tid; idx < PROW / 4; idx += 256) {   // 1173 float4s
    float4 v = row[idx];
    chain10(t, v.x); chain10(t, v.y); chain10(t, v.z); chain10(t, v.w);
  }
#pragma unroll
  for (int j = 0; j < 10; ++j) L[tid][j] = t[j];
  __syncthreads();
  for (int s = 1; s < 256; s <<= 1) {        // pairwise tree merge of sorted lists
    int i = tid * (s << 1);
    if (i + s < 256) {
      float tmp[10];
      int ia = 0, ib = 0;
#pragma unroll
      for (int j = 0; j < 10; ++j) {
        float va = L[i][ia], vb = L[i + s][ib];
        bool ga = va >= vb;
        tmp[j] = ga ? va : vb;
        if (ga) ia++; else ib++;
      }
#pragma unroll
      for (int j = 0; j < 10; ++j) L[i][j] = tmp[j];
    }
    __syncthreads();
  }
  if (tid == 0) {
    float s = 0.f;
#pragma unroll
    for (int j = 0; j < 10; ++j) s += L[0][j];
    out[b] = confs[b] * (s * 0.1f);
  }
}

// ---------- launch ----------

extern "C" void kernel_launch(void* const* d_in, const int* in_sizes, int n_in,
                              void* d_out, int out_size, void* d_ws, size_t ws_size,
                              hipStream_t stream) {
  const float* logits   = (const float*)d_in[0];
  const float* features = (const float*)d_in[1];
  const float* bank     = (const float*)d_in[2];
  float* out = (float*)d_out;

  // ws layout (~91 MB):
  //   confs    [0,        8192)
  //   featb8   [8192,     +2048*512 = 1 MB)
  //   bankb8   [1056768,  +100096*512 = 51.25 MB)
  //   partials [52305920, +2048*4692*4 = 38.4 MB)
  char* ws = (char*)d_ws;
  float* confs    = (float*)ws;
  u8*    featb8   = (u8*)(ws + 8192);
  u8*    bankb8   = (u8*)(ws + 8192 + (size_t)B_Q * D_DIM);
  float* partials = (float*)(ws + 8192 + (size_t)B_Q * D_DIM + (size_t)NPAD * D_DIM);

  // fused lse + feat cvt + bank cvt: 2048 + 256 + 12512 blocks
  pre_kernel<<<B_Q + 256 + NPAD * 32 / 256, 256, 0, stream>>>(
      logits, confs, features, featb8, bank, bankb8);

  gemm_topk_kernel<<<NBLOCKS, 256, 0, stream>>>(featb8, bankb8, partials);

  merge_kernel<<<B_Q, 256, 0, stream>>>(partials, confs, out);
}

// Round 14
// 618.714 us; speedup vs baseline: 1.4940x; 1.4940x over previous
//
#include <hip/hip_runtime.h>
#include <hip/hip_bf16.h>

// Problem constants
#define B_Q    2048
#define C_CLS  1000
#define D_DIM  512
#define N_BANK 100000
#define KSEL   10
#define NPAD   100096            // N_BANK padded to multiple of 128
#define NBLKS  782               // NPAD / 128
#define NBLOCKS (16 * NBLKS)     // 12512 workgroups (12512 % 8 == 0)
#define PROW   (NBLKS * 6)       // 4692 partial floats per query row

typedef __attribute__((ext_vector_type(4))) float  float4v;
typedef __attribute__((ext_vector_type(8))) int    int8v;
typedef unsigned short u16;
typedef unsigned int   u32;
typedef unsigned char  u8;

// ---------- helpers ----------

// f32 -> e4m3fn (OCP), RNE, flush |x|<2^-6 to 0 (inputs are N(0,1): negligible)
__device__ __forceinline__ u32 f2e4m3(float f) {
  union { float f; u32 u; } v; v.f = f;
  u32 u = v.u;
  u32 s = (u >> 24) & 0x80u;
  u32 a = u & 0x7FFFFFFFu;
  a += 0x7FFFFu + ((a >> 20) & 1u);        // RNE into 3-bit mantissa
  int e8 = (int)((a >> 23) & 0xFF) - 120;  // -127 + 7
  u32 r;
  if (e8 <= 0)       r = 0;
  else if (e8 >= 16) r = 0x7E;             // clamp to 448 (unreachable here)
  else               r = ((u32)e8 << 3) | ((a >> 20) & 7u);
  return s | r;
}

__device__ __forceinline__ u32 pack4_e4m3(float4 f) {
  return f2e4m3(f.x) | (f2e4m3(f.y) << 8) | (f2e4m3(f.z) << 16) | (f2e4m3(f.w) << 24);
}

__device__ __forceinline__ void chain10(float (&t)[10], float v) {
#pragma unroll
  for (int j = 0; j < 10; ++j) {
    float o = t[j];
    t[j] = fmaxf(o, v);
    v    = fminf(o, v);
  }
}

__device__ __forceinline__ void chain3(float (&t)[3], float v) {
#pragma unroll
  for (int j = 0; j < 3; ++j) {
    float o = t[j];
    t[j] = fmaxf(o, v);
    v    = fminf(o, v);
  }
}

__device__ __forceinline__ void load16(const u8* g, u8* l) {
  __builtin_amdgcn_global_load_lds(
      (const __attribute__((address_space(1))) unsigned int*)g,
      (__attribute__((address_space(3))) unsigned int*)l, 16, 0, 0);
}

// Permuted fp8 chunk writer for the BK=128 layout (proven R12/R13, absmax 8.0).
// Row layout: 512 B = 4 K-tiles x 128 B; K-tile = 8 slots of 16 B.
// Physical slot p holds logical slot L = p ^ (row&7). GEMM reads lo = L=g
// (p = g^swz8), hi = L=g+4 (p^4): 16 rows x 8 slots cover all 32 banks 2x
// -> conflict-free b128. Same permutation on A and B (any K-remap cancels).
__device__ __forceinline__ void cvt_chunk(const float* __restrict__ src,
                                          u8* __restrict__ dst, long idx, int nrows) {
  const int row = (int)(idx >> 5);
  const int c5  = (int)(idx & 31);
  const int kt  = c5 >> 3, p = c5 & 7;
  uint4 w;
  if (row < nrows) {
    const int L = p ^ (row & 7);
    const float* q = src + (long)row * D_DIM + kt * 128 + L * 16;
    w = make_uint4(pack4_e4m3(*(const float4*)(q)),
                   pack4_e4m3(*(const float4*)(q + 4)),
                   pack4_e4m3(*(const float4*)(q + 8)),
                   pack4_e4m3(*(const float4*)(q + 12)));
  } else {
    w = make_uint4(0, 0, 0, 0);
  }
  *(uint4*)(dst + idx * 16) = w;
}

// ---------- kernel 1: fused lse (0..2047) + feat cvt (2048..2303) + bank cvt ----------

__global__ __launch_bounds__(256) void pre_kernel(const float* __restrict__ logits,
                                                  float* __restrict__ confs,
                                                  const float* __restrict__ features,
                                                  u8* __restrict__ featb8,
                                                  const float* __restrict__ bank,
                                                  u8* __restrict__ bankb8) {
  const int tid = threadIdx.x;
  if (blockIdx.x < B_Q) {
    const int b = blockIdx.x;
    const int wid = tid >> 6, lane = tid & 63;
    const float* row = logits + (long)b * C_CLS;
    float x[4];
    float m = -INFINITY;
#pragma unroll
    for (int k = 0; k < 4; ++k) {
      int c = tid + k * 256;
      x[k] = (c < C_CLS) ? row[c] : -INFINITY;
      m = fmaxf(m, x[k]);
    }
#pragma unroll
    for (int off = 32; off; off >>= 1) m = fmaxf(m, __shfl_xor(m, off));
    __shared__ float redm[4], reds[4];
    if (lane == 0) redm[wid] = m;
    __syncthreads();
    m = fmaxf(fmaxf(redm[0], redm[1]), fmaxf(redm[2], redm[3]));
    float s = 0.f;
#pragma unroll
    for (int k = 0; k < 4; ++k) {
      int c = tid + k * 256;
      if (c < C_CLS) s += expf(x[k] - m);
    }
#pragma unroll
    for (int off = 32; off; off >>= 1) s += __shfl_xor(s, off);
    if (lane == 0) reds[wid] = s;
    __syncthreads();
    if (tid == 0) confs[b] = m + logf(reds[0] + reds[1] + reds[2] + reds[3]);
  } else if (blockIdx.x < B_Q + 256) {
    // feat cvt: 256 blocks = 65536 chunks (2048 rows x 32)
    long idx = (long)(blockIdx.x - B_Q) * 256 + tid;
    cvt_chunk(features, featb8, idx, B_Q);
  } else {
    // bank cvt: 12512 blocks = NPAD*32 chunks (pad rows zero-filled)
    long idx = (long)(blockIdx.x - B_Q - 256) * 256 + tid;
    cvt_chunk(bank, bankb8, idx, N_BANK);
  }
}

// ---------- epilogue helper: per-query top-3 over the wave's 64 banks ----------
// D (16x16 C/D layout, shape-determined): row = bank frag (g*4+reg), col = query
// (r16). chain3 over 16 lane-local values, merge across g-lanes via shfl 16/32.

template <bool MASKED>
__device__ __forceinline__ void epi(const float4v (&acc)[4][4], int bankbase,
                                    int qbase, int nblk, int wm, int g, int r16,
                                    float* __restrict__ partials) {
#pragma unroll
  for (int n = 0; n < 4; ++n) {
    float t3[3] = {-INFINITY, -INFINITY, -INFINITY};
#pragma unroll
    for (int mq = 0; mq < 4; ++mq)
#pragma unroll
      for (int reg = 0; reg < 4; ++reg) {
        float v = acc[mq][n][reg];
        if (MASKED) v = (bankbase + mq * 16 + reg < N_BANK) ? v : -INFINITY;
        chain3(t3, v);
      }
#pragma unroll
    for (int xm = 16; xm <= 32; xm <<= 1) {
      float o0 = __shfl_xor(t3[0], xm);
      float o1 = __shfl_xor(t3[1], xm);
      float o2 = __shfl_xor(t3[2], xm);
      chain3(t3, o0); chain3(t3, o1); chain3(t3, o2);
    }
    if (g == n) {
      const int q = qbase + n * 16 + r16;
      float* dst = partials + (long)q * PROW + nblk * 6 + wm * 3;
      dst[0] = t3[0]; dst[1] = t3[1]; dst[2] = t3[2];
    }
  }
}

// ---------- kernel 3: 128x128 MX-scaled fp8 GEMM, single-buffered, 3 blocks/CU ----------
//
// R13's structure (sync proven correct: absmax 8.0) with the spill fixed:
// __launch_bounds__(256,3) caps VGPR at ~170, fitting the ~130-reg live set
// (acc 64 + frags 40 + addressing) with NO scratch spill. R13's (256,4) cap
// of 128 forced the allocator to spill acc in the K-loop -> 4 GB scratch
// traffic (FETCH 1.5 GB / WRITE 2.6 GB / VGPR_Count 64 - the signature).
// Single-buffer 32 KB LDS -> LDS allows 5 blocks/CU; VGPR-bound at 3.
// MX arithmetic: mfma_scale_f32_16x16x128_f8f6f4, unit scales 0x7F.
// Global fp8 buffers pre-permuted (cvt_chunk): staging linear, swizzle baked.
// Swapped operands: D = sim[bank][query]. T1 XCD swizzle bijective.

struct __align__(16) SmemT {
  u8 A[128][128];   // 16 KB
  u8 B[128][128];   // 16 KB
};

__global__ __launch_bounds__(256, 3) void gemm_topk_kernel(const u8* __restrict__ featb8,
                                                           const u8* __restrict__ bankb8,
                                                           float* __restrict__ partials) {
  __shared__ SmemT sm;
  // T1: XCD-chunked bijective remap (XCD = blockIdx % 8 round-robin)
  const int orig = blockIdx.x;
  const int swid = (orig & 7) * (NBLOCKS / 8) + (orig >> 3);
  const int mblk = swid & 15;          // x-major: linear = mblk + 16*nblk
  const int nblk = swid >> 4;          // 0..781

  const int tid  = threadIdx.x;
  const int lane = tid & 63;
  const int wid  = tid >> 6;
  const int wm   = wid >> 1, wn = wid & 1;   // wave: banks wm*64.., queries wn*64..
  const int g    = lane >> 4, r16 = lane & 15;
  const int swz8 = r16 & 7;            // read-side slot-XOR term

  const u8* Ag = featb8 + (long)mblk * 128 * D_DIM;   // A = query tile (fp8, permuted)
  const u8* Bg = bankb8 + (long)nblk * 128 * D_DIM;   // B = bank tile  (fp8, permuted)

  float4v acc[4][4];                   // acc[mq][n]: mq = bank frag, n = query frag
  const float4v zero = {0.f, 0.f, 0.f, 0.f};
#pragma unroll
  for (int m = 0; m < 4; ++m)
#pragma unroll
    for (int n = 0; n < 4; ++n) acc[m][n] = zero;

  // staging: per K-tile each matrix is 1024 chunks of 16 B (row = c>>3, p = c&7);
  // buffers pre-permuted -> source linear: row*512 + kt*128 + p*16. 4 chunks/thread.
  long soff[4];
#pragma unroll
  for (int j = 0; j < 4; ++j) {
    const int c = tid + j * 256;
    soff[j] = (long)(c >> 3) * D_DIM + (c & 7) * 16;
  }

#define STAGE(ktv) do {                                                        \
    const int _k = (ktv) * 128;                                                \
    _Pragma("unroll")                                                          \
    for (int j = 0; j < 4; ++j)                                                \
      load16(Ag + soff[j] + _k, &sm.A[0][0] + (tid + j * 256) * 16);           \
    _Pragma("unroll")                                                          \
    for (int j = 0; j < 4; ++j)                                                \
      load16(Bg + soff[j] + _k, &sm.B[0][0] + (tid + j * 256) * 16);           \
  } while (0)

  // fragment: lo = logical slot g (p = g^swz8), hi = slot g+4 (p ^ 4)
#define FRAG(dstv, Mat, rowv) do {                                             \
    const u8* base_ = &sm.Mat[rowv][0];                                        \
    union { int8v v; uint4 q[2]; } u_;                                         \
    u_.q[0] = *(const uint4*)(base_ + ((g ^ swz8) * 16));                      \
    u_.q[1] = *(const uint4*)(base_ + (((g ^ swz8) ^ 4) * 16));                \
    dstv = u_.v;                                                               \
  } while (0)

#pragma unroll
  for (int kt = 0; kt < 4; ++kt) {
    STAGE(kt);
    asm volatile("s_waitcnt vmcnt(0)" ::: "memory");
    __builtin_amdgcn_s_barrier();
    __builtin_amdgcn_sched_barrier(0);
    {
      int8v af[4];
#pragma unroll
      for (int n = 0; n < 4; ++n) FRAG(af[n], A, wn * 64 + n * 16 + r16);
#pragma unroll
      for (int mq = 0; mq < 4; ++mq) {
        int8v bb;
        FRAG(bb, B, wm * 64 + mq * 16 + r16);
#pragma unroll
        for (int n = 0; n < 4; ++n)
          acc[mq][n] = __builtin_amdgcn_mfma_scale_f32_16x16x128_f8f6f4(
              bb, af[n], acc[mq][n], 0, 0, 0, 0x7F7F7F7F, 0, 0x7F7F7F7F);
      }
    }
    __builtin_amdgcn_sched_barrier(0);
    if (kt < 3) {
      __builtin_amdgcn_s_barrier();      // all waves done reading before overwrite
      __builtin_amdgcn_sched_barrier(0);
    }
  }

#undef STAGE
#undef FRAG

  // ---- in-register epilogue (uniform branch: pad masking only on last nblk) ----
  const int bankbase = nblk * 128 + wm * 64 + g * 4;
  const int qbase    = mblk * 128 + wn * 64;
  if (nblk == NBLKS - 1)
    epi<true >(acc, bankbase, qbase, nblk, wm, g, r16, partials);
  else
    epi<false>(acc, bankbase, qbase, nblk, wm, g, r16, partials);
}

// ---------- kernel 4: merge 782*6 partial values per row, scale, write out ----------

__global__ __launch_bounds__(256) void merge_kernel(const float* __restrict__ partials,
                                                    const float* __restrict__ confs,
                                                    float* __restrict__ out) {
  __shared__ float L[256][10];
  const int b = blockIdx.x, tid = threadIdx.x;
  const float4* row = (const float4*)(partials + (long)b * PROW);
  float t[10];
#pragma unroll
  for (int j = 0; j < 10; ++j) t[j] = -INFINITY;
  for (int idx = tid; idx < PROW / 4; idx += 256) {   // 1173 float4s
    float4 v = row[idx];
    chain10(t, v.x); chain10(t, v.y); chain10(t, v.z); chain10(t, v.w);
  }
#pragma unroll
  for (int j = 0; j < 10; ++j) L[tid][j] = t[j];
  __syncthreads();
  for (int s = 1; s < 256; s <<= 1) {        // pairwise tree merge of sorted lists
    int i = tid * (s << 1);
    if (i + s < 256) {
      float tmp[10];
      int ia = 0, ib = 0;
#pragma unroll
      for (int j = 0; j < 10; ++j) {
        float va = L[i][ia], vb = L[i + s][ib];
        bool ga = va >= vb;
        tmp[j] = ga ? va : vb;
        if (ga) ia++; else ib++;
      }
#pragma unroll
      for (int j = 0; j < 10; ++j) L[i][j] = tmp[j];
    }
    __syncthreads();
  }
  if (tid == 0) {
    float s = 0.f;
#pragma unroll
    for (int j = 0; j < 10; ++j) s += L[0][j];
    out[b] = confs[b] * (s * 0.1f);
  }
}

// ---------- launch ----------

extern "C" void kernel_launch(void* const* d_in, const int* in_sizes, int n_in,
                              void* d_out, int out_size, void* d_ws, size_t ws_size,
                              hipStream_t stream) {
  const float* logits   = (const float*)d_in[0];
  const float* features = (const float*)d_in[1];
  const float* bank     = (const float*)d_in[2];
  float* out = (float*)d_out;

  // ws layout (~91 MB):
  //   confs    [0,        8192)
  //   featb8   [8192,     +2048*512 = 1 MB)
  //   bankb8   [1056768,  +100096*512 = 51.25 MB)
  //   partials [52305920, +2048*4692*4 = 38.4 MB)
  char* ws = (char*)d_ws;
  float* confs    = (float*)ws;
  u8*    featb8   = (u8*)(ws + 8192);
  u8*    bankb8   = (u8*)(ws + 8192 + (size_t)B_Q * D_DIM);
  float* partials = (float*)(ws + 8192 + (size_t)B_Q * D_DIM + (size_t)NPAD * D_DIM);

  // fused lse + feat cvt + bank cvt: 2048 + 256 + 12512 blocks
  pre_kernel<<<B_Q + 256 + NPAD * 32 / 256, 256, 0, stream>>>(
      logits, confs, features, featb8, bank, bankb8);

  gemm_topk_kernel<<<NBLOCKS, 256, 0, stream>>>(featb8, bankb8, partials);

  merge_kernel<<<B_Q, 256, 0, stream>>>(partials, confs, out);
}

// Round 15
// 199.581 us; speedup vs baseline: 4.6315x; 3.1001x over previous
//
#include <hip/hip_runtime.h>
#include <hip/hip_bf16.h>

// Problem constants
#define B_Q    2048
#define C_CLS  1000
#define D_DIM  512
#define N_BANK 100000
#define KSEL   10
#define NPAD   100096            // N_BANK padded to multiple of 128
#define NBLKS  782               // NPAD / 128
#define NBLOCKS (16 * NBLKS)     // 12512 workgroups (12512 % 8 == 0)
#define PROW   (NBLKS * 6)       // 4692 partial floats per query row

typedef __attribute__((ext_vector_type(4))) float  float4v;
typedef __attribute__((ext_vector_type(8))) int    int8v;
typedef unsigned short u16;
typedef unsigned int   u32;
typedef unsigned char  u8;

// ---------- helpers ----------

// f32 -> e4m3fn (OCP), RNE, flush |x|<2^-6 to 0 (inputs are N(0,1): negligible)
__device__ __forceinline__ u32 f2e4m3(float f) {
  union { float f; u32 u; } v; v.f = f;
  u32 u = v.u;
  u32 s = (u >> 24) & 0x80u;
  u32 a = u & 0x7FFFFFFFu;
  a += 0x7FFFFu + ((a >> 20) & 1u);        // RNE into 3-bit mantissa
  int e8 = (int)((a >> 23) & 0xFF) - 120;  // -127 + 7
  u32 r;
  if (e8 <= 0)       r = 0;
  else if (e8 >= 16) r = 0x7E;             // clamp to 448 (unreachable here)
  else               r = ((u32)e8 << 3) | ((a >> 20) & 7u);
  return s | r;
}

__device__ __forceinline__ u32 pack4_e4m3(float4 f) {
  return f2e4m3(f.x) | (f2e4m3(f.y) << 8) | (f2e4m3(f.z) << 16) | (f2e4m3(f.w) << 24);
}

__device__ __forceinline__ void chain10(float (&t)[10], float v) {
#pragma unroll
  for (int j = 0; j < 10; ++j) {
    float o = t[j];
    t[j] = fmaxf(o, v);
    v    = fminf(o, v);
  }
}

__device__ __forceinline__ void chain3(float (&t)[3], float v) {
#pragma unroll
  for (int j = 0; j < 3; ++j) {
    float o = t[j];
    t[j] = fmaxf(o, v);
    v    = fminf(o, v);
  }
}

__device__ __forceinline__ void load16(const u8* g, u8* l) {
  __builtin_amdgcn_global_load_lds(
      (const __attribute__((address_space(1))) unsigned int*)g,
      (__attribute__((address_space(3))) unsigned int*)l, 16, 0, 0);
}

// Permuted fp8 chunk writer for the BK=128 layout (proven R12-R14, absmax 8.0).
// Row layout: 512 B = 4 K-tiles x 128 B; K-tile = 8 slots of 16 B.
// Physical slot p holds logical slot L = p ^ (row&7). GEMM reads lo = L=g
// (p = g^swz8), hi = L=g+4 (p^4): 16 rows x 8 slots cover all 32 banks 2x
// -> conflict-free b128. Same permutation on A and B (any K-remap cancels).
__device__ __forceinline__ void cvt_chunk(const float* __restrict__ src,
                                          u8* __restrict__ dst, long idx, int nrows) {
  const int row = (int)(idx >> 5);
  const int c5  = (int)(idx & 31);
  const int kt  = c5 >> 3, p = c5 & 7;
  uint4 w;
  if (row < nrows) {
    const int L = p ^ (row & 7);
    const float* q = src + (long)row * D_DIM + kt * 128 + L * 16;
    w = make_uint4(pack4_e4m3(*(const float4*)(q)),
                   pack4_e4m3(*(const float4*)(q + 4)),
                   pack4_e4m3(*(const float4*)(q + 8)),
                   pack4_e4m3(*(const float4*)(q + 12)));
  } else {
    w = make_uint4(0, 0, 0, 0);
  }
  *(uint4*)(dst + idx * 16) = w;
}

// ---------- kernel 1: fused lse (0..2047) + feat cvt (2048..2303) + bank cvt ----------

__global__ __launch_bounds__(256) void pre_kernel(const float* __restrict__ logits,
                                                  float* __restrict__ confs,
                                                  const float* __restrict__ features,
                                                  u8* __restrict__ featb8,
                                                  const float* __restrict__ bank,
                                                  u8* __restrict__ bankb8) {
  const int tid = threadIdx.x;
  if (blockIdx.x < B_Q) {
    const int b = blockIdx.x;
    const int wid = tid >> 6, lane = tid & 63;
    const float* row = logits + (long)b * C_CLS;
    float x[4];
    float m = -INFINITY;
#pragma unroll
    for (int k = 0; k < 4; ++k) {
      int c = tid + k * 256;
      x[k] = (c < C_CLS) ? row[c] : -INFINITY;
      m = fmaxf(m, x[k]);
    }
#pragma unroll
    for (int off = 32; off; off >>= 1) m = fmaxf(m, __shfl_xor(m, off));
    __shared__ float redm[4], reds[4];
    if (lane == 0) redm[wid] = m;
    __syncthreads();
    m = fmaxf(fmaxf(redm[0], redm[1]), fmaxf(redm[2], redm[3]));
    float s = 0.f;
#pragma unroll
    for (int k = 0; k < 4; ++k) {
      int c = tid + k * 256;
      if (c < C_CLS) s += expf(x[k] - m);
    }
#pragma unroll
    for (int off = 32; off; off >>= 1) s += __shfl_xor(s, off);
    if (lane == 0) reds[wid] = s;
    __syncthreads();
    if (tid == 0) confs[b] = m + logf(reds[0] + reds[1] + reds[2] + reds[3]);
  } else if (blockIdx.x < B_Q + 256) {
    // feat cvt: 256 blocks = 65536 chunks (2048 rows x 32)
    long idx = (long)(blockIdx.x - B_Q) * 256 + tid;
    cvt_chunk(features, featb8, idx, B_Q);
  } else {
    // bank cvt: 12512 blocks = NPAD*32 chunks (pad rows zero-filled)
    long idx = (long)(blockIdx.x - B_Q - 256) * 256 + tid;
    cvt_chunk(bank, bankb8, idx, N_BANK);
  }
}

// ---------- epilogue helper: per-query top-3 over the wave's 64 banks ----------
// D (16x16 C/D layout, shape-determined): row = bank frag (g*4+reg), col = query
// (r16). chain3 over 16 lane-local values, merge across g-lanes via shfl 16/32.

template <bool MASKED>
__device__ __forceinline__ void epi(const float4v (&acc)[4][4], int bankbase,
                                    int qbase, int nblk, int wm, int g, int r16,
                                    float* __restrict__ partials) {
#pragma unroll
  for (int n = 0; n < 4; ++n) {
    float t3[3] = {-INFINITY, -INFINITY, -INFINITY};
#pragma unroll
    for (int mq = 0; mq < 4; ++mq)
#pragma unroll
      for (int reg = 0; reg < 4; ++reg) {
        float v = acc[mq][n][reg];
        if (MASKED) v = (bankbase + mq * 16 + reg < N_BANK) ? v : -INFINITY;
        chain3(t3, v);
      }
#pragma unroll
    for (int xm = 16; xm <= 32; xm <<= 1) {
      float o0 = __shfl_xor(t3[0], xm);
      float o1 = __shfl_xor(t3[1], xm);
      float o2 = __shfl_xor(t3[2], xm);
      chain3(t3, o0); chain3(t3, o1); chain3(t3, o2);
    }
    if (g == n) {
      const int q = qbase + n * 16 + r16;
      float* dst = partials + (long)q * PROW + nblk * 6 + wm * 3;
      dst[0] = t3[0]; dst[1] = t3[1]; dst[2] = t3[2];
    }
  }
}

// ---------- kernel 3: 128x128 MX-scaled fp8 GEMM, single-buffered, relaxed bounds ----------
//
// R13/R14's single-buffer structure (sync proven: absmax 8.0) with R12's
// RELAXED register budget __launch_bounds__(256,2) (proven spill-free at
// 128 VGPR). Key insight: launch_bounds' 2nd arg is an allocator minimum,
// not an occupancy cap - actual occupancy = min(VGPR-derived, LDS-derived).
// At 128 VGPR the register file allows 4 waves/EU; single-buffer 32 KB LDS
// allows 5 blocks/CU -> 3-4 blocks/CU (vs R12's 2, capped by 64 KB dbuf).
// R13 (256,4) and R14 (256,3) both made the allocator spill acc to scratch
// (FETCH ~1 GB / WRITE ~1.5-2.6 GB signature); budget 256 does not.
// MX arithmetic: mfma_scale_f32_16x16x128_f8f6f4, unit scales 0x7F.
// Global fp8 buffers pre-permuted (cvt_chunk): staging linear, swizzle baked.
// Swapped operands: D = sim[bank][query]. T1 XCD swizzle bijective.

struct __align__(16) SmemT {
  u8 A[128][128];   // 16 KB
  u8 B[128][128];   // 16 KB
};

__global__ __launch_bounds__(256, 2) void gemm_topk_kernel(const u8* __restrict__ featb8,
                                                           const u8* __restrict__ bankb8,
                                                           float* __restrict__ partials) {
  __shared__ SmemT sm;
  // T1: XCD-chunked bijective remap (XCD = blockIdx % 8 round-robin)
  const int orig = blockIdx.x;
  const int swid = (orig & 7) * (NBLOCKS / 8) + (orig >> 3);
  const int mblk = swid & 15;          // x-major: linear = mblk + 16*nblk
  const int nblk = swid >> 4;          // 0..781

  const int tid  = threadIdx.x;
  const int lane = tid & 63;
  const int wid  = tid >> 6;
  const int wm   = wid >> 1, wn = wid & 1;   // wave: banks wm*64.., queries wn*64..
  const int g    = lane >> 4, r16 = lane & 15;
  const int swz8 = r16 & 7;            // read-side slot-XOR term

  const u8* Ag = featb8 + (long)mblk * 128 * D_DIM;   // A = query tile (fp8, permuted)
  const u8* Bg = bankb8 + (long)nblk * 128 * D_DIM;   // B = bank tile  (fp8, permuted)

  float4v acc[4][4];                   // acc[mq][n]: mq = bank frag, n = query frag
  const float4v zero = {0.f, 0.f, 0.f, 0.f};
#pragma unroll
  for (int m = 0; m < 4; ++m)
#pragma unroll
    for (int n = 0; n < 4; ++n) acc[m][n] = zero;

  // staging: per K-tile each matrix is 1024 chunks of 16 B (row = c>>3, p = c&7);
  // buffers pre-permuted -> source linear: row*512 + kt*128 + p*16. 4 chunks/thread.
  long soff[4];
#pragma unroll
  for (int j = 0; j < 4; ++j) {
    const int c = tid + j * 256;
    soff[j] = (long)(c >> 3) * D_DIM + (c & 7) * 16;
  }

#define STAGE(ktv) do {                                                        \
    const int _k = (ktv) * 128;                                                \
    _Pragma("unroll")                                                          \
    for (int j = 0; j < 4; ++j)                                                \
      load16(Ag + soff[j] + _k, &sm.A[0][0] + (tid + j * 256) * 16);           \
    _Pragma("unroll")                                                          \
    for (int j = 0; j < 4; ++j)                                                \
      load16(Bg + soff[j] + _k, &sm.B[0][0] + (tid + j * 256) * 16);           \
  } while (0)

  // fragment: lo = logical slot g (p = g^swz8), hi = slot g+4 (p ^ 4)
#define FRAG(dstv, Mat, rowv) do {                                             \
    const u8* base_ = &sm.Mat[rowv][0];                                        \
    union { int8v v; uint4 q[2]; } u_;                                         \
    u_.q[0] = *(const uint4*)(base_ + ((g ^ swz8) * 16));                      \
    u_.q[1] = *(const uint4*)(base_ + (((g ^ swz8) ^ 4) * 16));                \
    dstv = u_.v;                                                               \
  } while (0)

#pragma unroll
  for (int kt = 0; kt < 4; ++kt) {
    STAGE(kt);
    asm volatile("s_waitcnt vmcnt(0)" ::: "memory");
    __builtin_amdgcn_s_barrier();
    __builtin_amdgcn_sched_barrier(0);
    {
      int8v af[4];
#pragma unroll
      for (int n = 0; n < 4; ++n) FRAG(af[n], A, wn * 64 + n * 16 + r16);
#pragma unroll
      for (int mq = 0; mq < 4; ++mq) {
        int8v bb;
        FRAG(bb, B, wm * 64 + mq * 16 + r16);
#pragma unroll
        for (int n = 0; n < 4; ++n)
          acc[mq][n] = __builtin_amdgcn_mfma_scale_f32_16x16x128_f8f6f4(
              bb, af[n], acc[mq][n], 0, 0, 0, 0x7F7F7F7F, 0, 0x7F7F7F7F);
      }
    }
    __builtin_amdgcn_sched_barrier(0);
    if (kt < 3) {
      __builtin_amdgcn_s_barrier();      // all waves done reading before overwrite
      __builtin_amdgcn_sched_barrier(0);
    }
  }

#undef STAGE
#undef FRAG

  // ---- in-register epilogue (uniform branch: pad masking only on last nblk) ----
  const int bankbase = nblk * 128 + wm * 64 + g * 4;
  const int qbase    = mblk * 128 + wn * 64;
  if (nblk == NBLKS - 1)
    epi<true >(acc, bankbase, qbase, nblk, wm, g, r16, partials);
  else
    epi<false>(acc, bankbase, qbase, nblk, wm, g, r16, partials);
}

// ---------- kernel 4: merge 782*6 partial values per row, scale, write out ----------

__global__ __launch_bounds__(256) void merge_kernel(const float* __restrict__ partials,
                                                    const float* __restrict__ confs,
                                                    float* __restrict__ out) {
  __shared__ float L[256][10];
  const int b = blockIdx.x, tid = threadIdx.x;
  const float4* row = (const float4*)(partials + (long)b * PROW);
  float t[10];
#pragma unroll
  for (int j = 0; j < 10; ++j) t[j] = -INFINITY;
  for (int idx = tid; idx < PROW / 4; idx += 256) {   // 1173 float4s
    float4 v = row[idx];
    chain10(t, v.x); chain10(t, v.y); chain10(t, v.z); chain10(t, v.w);
  }
#pragma unroll
  for (int j = 0; j < 10; ++j) L[tid][j] = t[j];
  __syncthreads();
  for (int s = 1; s < 256; s <<= 1) {        // pairwise tree merge of sorted lists
    int i = tid * (s << 1);
    if (i + s < 256) {
      float tmp[10];
      int ia = 0, ib = 0;
#pragma unroll
      for (int j = 0; j < 10; ++j) {
        float va = L[i][ia], vb = L[i + s][ib];
        bool ga = va >= vb;
        tmp[j] = ga ? va : vb;
        if (ga) ia++; else ib++;
      }
#pragma unroll
      for (int j = 0; j < 10; ++j) L[i][j] = tmp[j];
    }
    __syncthreads();
  }
  if (tid == 0) {
    float s = 0.f;
#pragma unroll
    for (int j = 0; j < 10; ++j) s += L[0][j];
    out[b] = confs[b] * (s * 0.1f);
  }
}

// ---------- launch ----------

extern "C" void kernel_launch(void* const* d_in, const int* in_sizes, int n_in,
                              void* d_out, int out_size, void* d_ws, size_t ws_size,
                              hipStream_t stream) {
  const float* logits   = (const float*)d_in[0];
  const float* features = (const float*)d_in[1];
  const float* bank     = (const float*)d_in[2];
  float* out = (float*)d_out;

  // ws layout (~91 MB):
  //   confs    [0,        8192)
  //   featb8   [8192,     +2048*512 = 1 MB)
  //   bankb8   [1056768,  +100096*512 = 51.25 MB)
  //   partials [52305920, +2048*4692*4 = 38.4 MB)
  char* ws = (char*)d_ws;
  float* confs    = (float*)ws;
  u8*    featb8   = (u8*)(ws + 8192);
  u8*    bankb8   = (u8*)(ws + 8192 + (size_t)B_Q * D_DIM);
  float* partials = (float*)(ws + 8192 + (size_t)B_Q * D_DIM + (size_t)NPAD * D_DIM);

  // fused lse + feat cvt + bank cvt: 2048 + 256 + 12512 blocks
  pre_kernel<<<B_Q + 256 + NPAD * 32 / 256, 256, 0, stream>>>(
      logits, confs, features, featb8, bank, bankb8);

  gemm_topk_kernel<<<NBLOCKS, 256, 0, stream>>>(featb8, bankb8, partials);

  merge_kernel<<<B_Q, 256, 0, stream>>>(partials, confs, out);
}